// Round 1
// baseline (2109.901 us; speedup 1.0000x reference)
//
#include <hip/hip_runtime.h>
#include <hip/hip_bf16.h>

#define DEVFN __device__ __forceinline__

constexpr int NN = 50000;
constexpr int NE = 800000;
constexpr int NQ = 200000;

DEVFN float lrelu(float x) { return x > 0.f ? x : 0.01f * x; }
DEVFN float sigmoidf(float x) { return 1.f / (1.f + __expf(-x)); }

// ---------------------------------------------------------------------------
// Generic tiled fp32 GEMM: C[M,N] = epi(A[M,K] @ B[K,N] + bias)
// BM=64, BN=64, BK=16, 256 threads, 4x4 per thread.
// EPI: 0 = none, 1 = bias + leaky_relu
// ---------------------------------------------------------------------------
template <int EPI>
__global__ void gemm64(const float* __restrict__ A, const float* __restrict__ B,
                       const float* __restrict__ bias, float* __restrict__ C,
                       int M, int N, int K) {
    constexpr int BM = 64, BN = 64, BK = 16;
    __shared__ float As[BK][BM];
    __shared__ float Bs[BK][BN];
    const int tid = threadIdx.x;
    const int tx = tid & 15, ty = tid >> 4;
    const int row0 = blockIdx.x * BM, col0 = blockIdx.y * BN;
    float acc[4][4] = {};
    const int arow = row0 + (tid >> 2);
    const int ak = (tid & 3) * 4;
    const int bk = tid >> 4;          // 0..15
    const int bn = (tid & 15) * 4;    // 0..60

    for (int k0 = 0; k0 < K; k0 += BK) {
        float4 av = make_float4(0.f, 0.f, 0.f, 0.f);
        if (arow < M) av = *(const float4*)&A[(long)arow * K + k0 + ak];
        As[ak + 0][tid >> 2] = av.x;
        As[ak + 1][tid >> 2] = av.y;
        As[ak + 2][tid >> 2] = av.z;
        As[ak + 3][tid >> 2] = av.w;
        *(float4*)&Bs[bk][bn] = *(const float4*)&B[(long)(k0 + bk) * N + col0 + bn];
        __syncthreads();
#pragma unroll
        for (int kk = 0; kk < BK; ++kk) {
            float a[4], b[4];
            *(float4*)a = *(const float4*)&As[kk][ty * 4];
            *(float4*)b = *(const float4*)&Bs[kk][tx * 4];
#pragma unroll
            for (int i = 0; i < 4; ++i)
#pragma unroll
                for (int j = 0; j < 4; ++j)
                    acc[i][j] = fmaf(a[i], b[j], acc[i][j]);
        }
        __syncthreads();
    }

#pragma unroll
    for (int i = 0; i < 4; ++i) {
        int r = row0 + ty * 4 + i;
        if (r >= M) continue;
        float4 v;
        float* vp = (float*)&v;
#pragma unroll
        for (int j = 0; j < 4; ++j) {
            int c = col0 + tx * 4 + j;
            float t = acc[i][j];
            if (EPI == 1) { t += bias[c]; t = lrelu(t); }
            vp[j] = t;
        }
        *(float4*)&C[(long)r * N + col0 + tx * 4] = v;
    }
}

// ---------------------------------------------------------------------------
// Fused GRU cell: out = (1-z)*n + z*prev, gates from h@Wih+bih, prev@Whh+bhh
// Block computes 64 rows x 64 gate-cols across all 3 gates of both matmuls
// (6 accumulator tiles), then applies gating in the epilogue.
// Wih/Whh are [H, 3H] with gate order (r, z, n).
// ---------------------------------------------------------------------------
template <int H>
__global__ __launch_bounds__(256, 1)
void gru_fused(const float* __restrict__ h, const float* __restrict__ prev,
               const float* __restrict__ Wih, const float* __restrict__ Whh,
               const float* __restrict__ bih, const float* __restrict__ bhh,
               float* __restrict__ out, int M) {
    constexpr int BM = 64, BN = 64, BK = 16, K = H, W3 = 3 * H;
    __shared__ float Ah[BK][BM];
    __shared__ float Ap[BK][BM];
    __shared__ float Bsh[6][BK][BN];
    const int tid = threadIdx.x;
    const int tx = tid & 15, ty = tid >> 4;
    const int row0 = blockIdx.x * BM, col0 = blockIdx.y * BN;
    float acc[6][4][4] = {};
    const int arow = row0 + (tid >> 2);
    const int ak = (tid & 3) * 4;
    const int bk = tid >> 4;
    const int bn = (tid & 15) * 4;

    for (int k0 = 0; k0 < K; k0 += BK) {
        float4 av = make_float4(0.f, 0.f, 0.f, 0.f);
        float4 pv = make_float4(0.f, 0.f, 0.f, 0.f);
        if (arow < M) {
            av = *(const float4*)&h[(long)arow * K + k0 + ak];
            pv = *(const float4*)&prev[(long)arow * K + k0 + ak];
        }
        Ah[ak + 0][tid >> 2] = av.x; Ah[ak + 1][tid >> 2] = av.y;
        Ah[ak + 2][tid >> 2] = av.z; Ah[ak + 3][tid >> 2] = av.w;
        Ap[ak + 0][tid >> 2] = pv.x; Ap[ak + 1][tid >> 2] = pv.y;
        Ap[ak + 2][tid >> 2] = pv.z; Ap[ak + 3][tid >> 2] = pv.w;
        const long wrow = (long)(k0 + bk) * W3 + col0 + bn;
#pragma unroll
        for (int g = 0; g < 3; ++g) {
            *(float4*)&Bsh[g][bk][bn]     = *(const float4*)&Wih[wrow + g * H];
            *(float4*)&Bsh[3 + g][bk][bn] = *(const float4*)&Whh[wrow + g * H];
        }
        __syncthreads();
#pragma unroll
        for (int kk = 0; kk < BK; ++kk) {
            float ah[4], ap[4], b[6][4];
            *(float4*)ah = *(const float4*)&Ah[kk][ty * 4];
            *(float4*)ap = *(const float4*)&Ap[kk][ty * 4];
#pragma unroll
            for (int m = 0; m < 6; ++m)
                *(float4*)b[m] = *(const float4*)&Bsh[m][kk][tx * 4];
#pragma unroll
            for (int i = 0; i < 4; ++i) {
#pragma unroll
                for (int j = 0; j < 4; ++j) {
                    acc[0][i][j] = fmaf(ah[i], b[0][j], acc[0][i][j]);
                    acc[1][i][j] = fmaf(ah[i], b[1][j], acc[1][i][j]);
                    acc[2][i][j] = fmaf(ah[i], b[2][j], acc[2][i][j]);
                    acc[3][i][j] = fmaf(ap[i], b[3][j], acc[3][i][j]);
                    acc[4][i][j] = fmaf(ap[i], b[4][j], acc[4][i][j]);
                    acc[5][i][j] = fmaf(ap[i], b[5][j], acc[5][i][j]);
                }
            }
        }
        __syncthreads();
    }

#pragma unroll
    for (int i = 0; i < 4; ++i) {
        int r = row0 + ty * 4 + i;
        if (r >= M) continue;
#pragma unroll
        for (int j = 0; j < 4; ++j) {
            int c = col0 + tx * 4 + j;
            float ir = acc[0][i][j] + bih[c];
            float iz = acc[1][i][j] + bih[H + c];
            float in_ = acc[2][i][j] + bih[2 * H + c];
            float hr = acc[3][i][j] + bhh[c];
            float hz = acc[4][i][j] + bhh[H + c];
            float hn = acc[5][i][j] + bhh[2 * H + c];
            float rg = sigmoidf(ir + hr);
            float zg = sigmoidf(iz + hz);
            float ng = tanhf(in_ + rg * hn);
            out[(long)r * H + c] = (1.f - zg) * ng + zg * prev[(long)r * H + c];
        }
    }
}

// ---------------------------------------------------------------------------
// Degree count (edges only; +1 self loop added in dinv pass)
// ---------------------------------------------------------------------------
__global__ void deg_kernel(const int* __restrict__ cols, float* __restrict__ deg, int E) {
    int e = blockIdx.x * 256 + threadIdx.x;
    if (e < E) atomicAdd(&deg[cols[e]], 1.0f);
}

__global__ void dinv_kernel(float* __restrict__ deg, int n) {
    int i = blockIdx.x * 256 + threadIdx.x;
    if (i < n) deg[i] = rsqrtf(deg[i] + 1.0f);   // deg includes self-loop -> >= 1
}

// ---------------------------------------------------------------------------
// Scatter: agg[col_e] += hw[row_e] * dinv[row_e]*dinv[col_e]   (64 lanes/edge)
// ---------------------------------------------------------------------------
template <int H>
__global__ void scatter_kernel(const float* __restrict__ hw, const int* __restrict__ rows,
                               const int* __restrict__ cols, const float* __restrict__ dinv,
                               float* __restrict__ agg, int E) {
    int t = blockIdx.x * 256 + threadIdx.x;
    int e = t >> 6, l = t & 63;
    if (e >= E) return;
    int r = rows[e], c = cols[e];
    float nrm = dinv[r] * dinv[c];
#pragma unroll
    for (int i = 0; i < H / 64; ++i)
        atomicAdd(&agg[(long)c * H + l + 64 * i], hw[(long)r * H + l + 64 * i] * nrm);
}

// ---------------------------------------------------------------------------
// Self-loop + bias + leaky_relu: agg = lrelu(agg + hw*dinv^2 + bias)
// ---------------------------------------------------------------------------
template <int H>
__global__ void finish_agg(float* __restrict__ agg, const float* __restrict__ hw,
                           const float* __restrict__ dinv, const float* __restrict__ bias,
                           int n) {
    int t = blockIdx.x * 256 + threadIdx.x;
    if (t >= n * H) return;
    int i = t / H, f = t % H;
    float d = dinv[i];
    float v = agg[t] + hw[t] * d * d + bias[f];
    agg[t] = lrelu(v);
}

// ---------------------------------------------------------------------------
// Edge scores: one 64-lane wave per query edge; 272-dim dot with post_W
// ---------------------------------------------------------------------------
__global__ void edge_score(const float* __restrict__ emb2, const int* __restrict__ eli,
                           const float* __restrict__ ea, const float* __restrict__ pw,
                           const float* __restrict__ pb, float* __restrict__ scores, int Q) {
    int t = blockIdx.x * 256 + threadIdx.x;
    int e = t >> 6, l = t & 63;
    if (e >= Q) return;
    int s = eli[e], d = eli[Q + e];
    float acc = 0.f;
#pragma unroll
    for (int i = 0; i < 2; ++i) {
        int f = l + 64 * i;
        acc += emb2[(long)s * 128 + f] * pw[f] + emb2[(long)d * 128 + f] * pw[128 + f];
    }
    if (l < 16) acc += ea[(long)e * 16 + l] * pw[256 + l];
#pragma unroll
    for (int off = 32; off > 0; off >>= 1) acc += __shfl_down(acc, off);
    if (l == 0) scores[e] = acc + pb[0];
}

// ---------------------------------------------------------------------------

extern "C" void kernel_launch(void* const* d_in, const int* in_sizes, int n_in,
                              void* d_out, int out_size, void* d_ws, size_t ws_size,
                              hipStream_t stream) {
    const float* x       = (const float*)d_in[0];
    const int*   ei      = (const int*)d_in[1];    // [2, E] (jax int64 demoted to int32)
    const int*   eli     = (const int*)d_in[2];    // [2, EQ]
    const float* eattr   = (const float*)d_in[3];
    const float* prev1   = (const float*)d_in[4];
    const float* prev2   = (const float*)d_in[5];
    const float* pre1_W  = (const float*)d_in[6];
    const float* pre1_b  = (const float*)d_in[7];
    const float* pre2_W  = (const float*)d_in[8];
    const float* pre2_b  = (const float*)d_in[9];
    const float* conv1_W = (const float*)d_in[10];
    const float* conv1_b = (const float*)d_in[11];
    const float* conv2_W = (const float*)d_in[12];
    const float* conv2_b = (const float*)d_in[13];
    const float* g1_Wih  = (const float*)d_in[14];
    const float* g1_Whh  = (const float*)d_in[15];
    const float* g1_bih  = (const float*)d_in[16];
    const float* g1_bhh  = (const float*)d_in[17];
    const float* g2_Wih  = (const float*)d_in[18];
    const float* g2_Whh  = (const float*)d_in[19];
    const float* g2_bih  = (const float*)d_in[20];
    const float* g2_bhh  = (const float*)d_in[21];
    const float* post_W  = (const float*)d_in[22];
    const float* post_b  = (const float*)d_in[23];

    float* out    = (float*)d_out;
    float* scores = out;                         // [NQ]
    float* emb1   = out + NQ;                    // [N, 256]
    float* emb2   = emb1 + (long)NN * 256;       // [N, 128]

    float* bufA = (float*)d_ws;                  // [N, 256]
    float* bufB = bufA + (long)NN * 256;         // [N, 256]
    float* bufC = bufB + (long)NN * 256;         // [N, 128]
    float* dinv = bufC + (long)NN * 128;         // [N]

    const int* rows = ei;        // edge_index[0]
    const int* cols = ei + NE;   // edge_index[1]

    dim3 blk(256);
    const int mb = (NN + 63) / 64;   // 782

    // h1 = lrelu(x @ pre1_W + b)           -> bufA [N,256]
    gemm64<1><<<dim3(mb, 4), blk, 0, stream>>>(x, pre1_W, pre1_b, bufA, NN, 256, 256);
    // h2 = lrelu(h1 @ pre2_W + b)          -> bufC [N,128]
    gemm64<1><<<dim3(mb, 2), blk, 0, stream>>>(bufA, pre2_W, pre2_b, bufC, NN, 128, 256);
    // hw1 = h2 @ conv1_W                   -> bufB [N,256]
    gemm64<0><<<dim3(mb, 4), blk, 0, stream>>>(bufC, conv1_W, nullptr, bufB, NN, 256, 128);

    // degrees -> dinv
    hipMemsetAsync(dinv, 0, NN * sizeof(float), stream);
    deg_kernel<<<(NE + 255) / 256, blk, 0, stream>>>(cols, dinv, NE);
    dinv_kernel<<<(NN + 255) / 256, blk, 0, stream>>>(dinv, NN);

    // agg1 = A_hat @ hw1                   -> bufA [N,256]
    hipMemsetAsync(bufA, 0, (size_t)NN * 256 * sizeof(float), stream);
    scatter_kernel<256><<<NE / 4, blk, 0, stream>>>(bufB, rows, cols, dinv, bufA, NE);
    finish_agg<256><<<(NN * 256 + 255) / 256, blk, 0, stream>>>(bufA, bufB, dinv, conv1_b, NN);

    // emb1 = GRU(agg1, prev1)              -> d_out
    gru_fused<256><<<dim3(mb, 4), blk, 0, stream>>>(bufA, prev1, g1_Wih, g1_Whh,
                                                    g1_bih, g1_bhh, emb1, NN);

    // hw2 = emb1 @ conv2_W                 -> bufC [N,128]
    gemm64<0><<<dim3(mb, 2), blk, 0, stream>>>(emb1, conv2_W, nullptr, bufC, NN, 128, 256);

    // agg2 = A_hat @ hw2                   -> bufB [N,128]
    hipMemsetAsync(bufB, 0, (size_t)NN * 128 * sizeof(float), stream);
    scatter_kernel<128><<<NE / 4, blk, 0, stream>>>(bufC, rows, cols, dinv, bufB, NE);
    finish_agg<128><<<(NN * 128 + 255) / 256, blk, 0, stream>>>(bufB, bufC, dinv, conv2_b, NN);

    // emb2 = GRU(agg2, prev2)              -> d_out
    gru_fused<128><<<dim3(mb, 2), blk, 0, stream>>>(bufB, prev2, g2_Wih, g2_Whh,
                                                    g2_bih, g2_bhh, emb2, NN);

    // scores
    edge_score<<<NQ / 4, blk, 0, stream>>>(emb2, eli, eattr, post_W, post_b, scores, NQ);
}

// Round 2
// 1430.393 us; speedup vs baseline: 1.4751x; 1.4751x over previous
//
#include <hip/hip_runtime.h>
#include <hip/hip_bf16.h>

#define DEVFN __device__ __forceinline__

constexpr int NN = 50000;
constexpr int NE = 800000;
constexpr int NQ = 200000;
constexpr long MP = 50048;   // NN padded to multiple of 128

typedef __attribute__((ext_vector_type(8))) short bf16x8;
typedef __attribute__((ext_vector_type(4))) float f32x4;
typedef __attribute__((address_space(1))) const void gv_t;
typedef __attribute__((address_space(3))) void lv_t;

DEVFN float lrelu(float x) { return x > 0.f ? x : 0.01f * x; }
DEVFN float sigmoidf(float x) { return 1.f / (1.f + __expf(-x)); }

DEVFN short f2b(float v) {
    __hip_bfloat16 h = __float2bfloat16(v);
    return *reinterpret_cast<short*>(&h);
}
DEVFN float b2f(short s) {
    union { unsigned u; float f; } z;
    z.u = ((unsigned)(unsigned short)s) << 16;
    return z.f;
}
DEVFN void gld16(const void* g, void* l) {
    __builtin_amdgcn_global_load_lds((gv_t*)g, (lv_t*)l, 16, 0, 0);
}

// ---------------------------------------------------------------------------
// fp32 -> bf16 row copy with zero-filled padding rows
// ---------------------------------------------------------------------------
__global__ void f2b_rows(const float* __restrict__ in, short* __restrict__ out,
                         long n, long ntot) {
    long i = (long)blockIdx.x * 256 + threadIdx.x;
    if (i < n) out[i] = f2b(in[i]);
    else if (i < ntot) out[i] = 0;
}

// fp32 [K][N] -> bf16 [N][K] (transposed weights)
__global__ void wT_b(const float* __restrict__ W, short* __restrict__ Wt, int K, int N) {
    int i = blockIdx.x * 256 + threadIdx.x;
    if (i >= N * K) return;
    int n = i / K, k = i % K;
    Wt[i] = f2b(W[(long)k * N + n]);
}

// ---------------------------------------------------------------------------
// bf16 MFMA GEMM: C = epi(A[Mpad][K] @ Bt[Nt][K]^T + bias)
// BM=BN=128, BK=32, 4 waves (2x2), each wave 64x64 (4x4 16x16 frags).
// EPI: 0 none, 1 bias+lrelu.  OUTF: write fp32 rows<M.  OUTB: write bf16 all rows.
// ---------------------------------------------------------------------------
template <int EPI, bool OUTF, bool OUTB>
__global__ __launch_bounds__(256)
void gemm_mfma(const short* __restrict__ A, const short* __restrict__ Bt,
               const float* __restrict__ bias, float* __restrict__ Cf,
               short* __restrict__ Cb, int M, int Nt, int K) {
    __shared__ alignas(16) short As[128 * 32];
    __shared__ alignas(16) short Bs[128 * 32];
    const int tid = threadIdx.x;
    const int lane = tid & 63, w = tid >> 6;
    const int wr = w >> 1, wc = w & 1;
    const long row0 = (long)blockIdx.x * 128;
    const long col0 = (long)blockIdx.y * 128;

    f32x4 acc[4][4] = {};

    const int ra = tid >> 2;            // 0..63
    const int kc = (tid & 3) * 8;       // element offset in K
    const short* gA = A + (row0 + ra) * (long)K + kc;
    const short* gB = Bt + (col0 + ra) * (long)K + kc;
    short* lA0 = As + tid * 8;
    short* lA1 = As + 2048 + tid * 8;
    short* lB0 = Bs + tid * 8;
    short* lB1 = Bs + 2048 + tid * 8;
    const long half = 64 * (long)K;

    for (int k0 = 0; k0 < K; k0 += 32) {
        gld16(gA + k0, lA0);
        gld16(gA + half + k0, lA1);
        gld16(gB + k0, lB0);
        gld16(gB + half + k0, lB1);
        __syncthreads();
        bf16x8 af[4], bfr[4];
        const int l15 = lane & 15, kq = (lane >> 4) * 8;
#pragma unroll
        for (int i = 0; i < 4; ++i)
            af[i] = *(const bf16x8*)&As[(wr * 64 + i * 16 + l15) * 32 + kq];
#pragma unroll
        for (int j = 0; j < 4; ++j)
            bfr[j] = *(const bf16x8*)&Bs[(wc * 64 + j * 16 + l15) * 32 + kq];
#pragma unroll
        for (int i = 0; i < 4; ++i)
#pragma unroll
            for (int j = 0; j < 4; ++j)
                acc[i][j] = __builtin_amdgcn_mfma_f32_16x16x32_bf16(af[i], bfr[j], acc[i][j], 0, 0, 0);
        __syncthreads();
    }

    const int cr = (lane >> 4) * 4, cc = lane & 15;
#pragma unroll
    for (int i = 0; i < 4; ++i) {
#pragma unroll
        for (int j = 0; j < 4; ++j) {
            const long col = col0 + wc * 64 + j * 16 + cc;
            float bv = (EPI == 1) ? bias[col] : 0.f;
#pragma unroll
            for (int r = 0; r < 4; ++r) {
                const long row = row0 + wr * 64 + i * 16 + cr + r;
                float v = acc[i][j][r];
                if (EPI == 1) v = lrelu(v + bv);
                if (OUTF && row < M) Cf[row * Nt + col] = v;
                if (OUTB) Cb[row * Nt + col] = f2b(v);
            }
        }
    }
}

// ---------------------------------------------------------------------------
// Fused GRU via MFMA: 6 acc tile-sets (gi_r,gi_z,gi_n from Ab; gh_* from Pb)
// Tile 64 rows x 64 gate-cols, 4 waves (2x2), each wave 32x32 per set.
// WihT/WhhT are [3H][H] bf16 (transposed).
// ---------------------------------------------------------------------------
template <int H, bool WRITEB>
__global__ __launch_bounds__(256)
void gru_mfma(const short* __restrict__ Ab, const short* __restrict__ Pb,
              const float* __restrict__ prevf,
              const short* __restrict__ WihT, const short* __restrict__ WhhT,
              const float* __restrict__ bih, const float* __restrict__ bhh,
              float* __restrict__ outF, short* __restrict__ outB, int M) {
    __shared__ alignas(16) short Ah[64 * 32];
    __shared__ alignas(16) short Ap[64 * 32];
    __shared__ alignas(16) short Bs6[6][64 * 32];
    const int tid = threadIdx.x;
    const int lane = tid & 63, w = tid >> 6;
    const int wr = w >> 1, wc = w & 1;
    const long row0 = (long)blockIdx.x * 64;
    const int col0 = blockIdx.y * 64;

    f32x4 acc[6][2][2] = {};

    const int ra = tid >> 2;
    const int kc = (tid & 3) * 8;
    const short* gA = Ab + (row0 + ra) * (long)H + kc;
    const short* gP = Pb + (row0 + ra) * (long)H + kc;
    const short* gW[6];
#pragma unroll
    for (int g = 0; g < 3; ++g) {
        gW[g]     = WihT + (long)(g * H + col0 + ra) * H + kc;
        gW[3 + g] = WhhT + (long)(g * H + col0 + ra) * H + kc;
    }
    short* lA = Ah + tid * 8;
    short* lP = Ap + tid * 8;

    for (int k0 = 0; k0 < H; k0 += 32) {
        gld16(gA + k0, lA);
        gld16(gP + k0, lP);
#pragma unroll
        for (int m = 0; m < 6; ++m)
            gld16(gW[m] + k0, &Bs6[m][tid * 8]);
        __syncthreads();
        const int l15 = lane & 15, kq = (lane >> 4) * 8;
        bf16x8 a2[2], p2[2], bb[6][2];
#pragma unroll
        for (int i = 0; i < 2; ++i) {
            a2[i] = *(const bf16x8*)&Ah[(wr * 32 + i * 16 + l15) * 32 + kq];
            p2[i] = *(const bf16x8*)&Ap[(wr * 32 + i * 16 + l15) * 32 + kq];
        }
#pragma unroll
        for (int m = 0; m < 6; ++m)
#pragma unroll
            for (int j = 0; j < 2; ++j)
                bb[m][j] = *(const bf16x8*)&Bs6[m][(wc * 32 + j * 16 + l15) * 32 + kq];
#pragma unroll
        for (int m = 0; m < 6; ++m)
#pragma unroll
            for (int i = 0; i < 2; ++i)
#pragma unroll
                for (int j = 0; j < 2; ++j)
                    acc[m][i][j] = __builtin_amdgcn_mfma_f32_16x16x32_bf16(
                        (m < 3) ? a2[i] : p2[i], bb[m][j], acc[m][i][j], 0, 0, 0);
        __syncthreads();
    }

    const int cr = (lane >> 4) * 4, cc = lane & 15;
#pragma unroll
    for (int i = 0; i < 2; ++i) {
#pragma unroll
        for (int j = 0; j < 2; ++j) {
            const long col = col0 + wc * 32 + j * 16 + cc;
            const float bi_r = bih[col], bi_z = bih[H + col], bi_n = bih[2 * H + col];
            const float bh_r = bhh[col], bh_z = bhh[H + col], bh_n = bhh[2 * H + col];
#pragma unroll
            for (int r = 0; r < 4; ++r) {
                const long row = row0 + wr * 32 + i * 16 + cr + r;
                if (row >= M) continue;
                float rg = sigmoidf(acc[0][i][j][r] + bi_r + acc[3][i][j][r] + bh_r);
                float zg = sigmoidf(acc[1][i][j][r] + bi_z + acc[4][i][j][r] + bh_z);
                float ng = tanhf(acc[2][i][j][r] + bi_n + rg * (acc[5][i][j][r] + bh_n));
                float o = (1.f - zg) * ng + zg * prevf[row * (long)H + col];
                outF[row * (long)H + col] = o;
                if (WRITEB) outB[row * (long)H + col] = f2b(o);
            }
        }
    }
}

// ---------------------------------------------------------------------------
// Degree / normalization
// ---------------------------------------------------------------------------
__global__ void deg_kernel(const int* __restrict__ cols, float* __restrict__ deg, int E) {
    int e = blockIdx.x * 256 + threadIdx.x;
    if (e < E) atomicAdd(&deg[cols[e]], 1.0f);
}
__global__ void dinv_kernel(float* __restrict__ deg, int n) {
    int i = blockIdx.x * 256 + threadIdx.x;
    if (i < n) deg[i] = rsqrtf(deg[i] + 1.0f);
}

// ---------------------------------------------------------------------------
// Scatter (bf16 gather, fp32 atomic accumulate): agg[c] += hw[r]*dinv[r]*dinv[c]
// ---------------------------------------------------------------------------
template <int H>
__global__ void scatter_b(const short* __restrict__ hwb, const int* __restrict__ rows,
                          const int* __restrict__ cols, const float* __restrict__ dinv,
                          float* __restrict__ agg, int E) {
    int t = blockIdx.x * 256 + threadIdx.x;
    int e = t >> 6, l = t & 63;
    if (e >= E) return;
    int r = rows[e], c = cols[e];
    float nrm = dinv[r] * dinv[c];
#pragma unroll
    for (int i = 0; i < H / 64; ++i)
        atomicAdd(&agg[(long)c * H + l + 64 * i], b2f(hwb[(long)r * H + l + 64 * i]) * nrm);
}

// agg(out-region fp32) + self-loop + bias + lrelu -> bf16
template <int H>
__global__ void finish_agg_b(const float* __restrict__ agg, const short* __restrict__ hwb,
                             const float* __restrict__ dinv, const float* __restrict__ bias,
                             short* __restrict__ outb, long n) {
    long t = (long)blockIdx.x * 256 + threadIdx.x;
    if (t >= n * H) return;
    long i = t / H;
    int f = t % H;
    float d = dinv[i];
    float v = agg[t] + b2f(hwb[t]) * d * d + bias[f];
    outb[t] = f2b(lrelu(v));
}

// ---------------------------------------------------------------------------
// Edge scores: one 64-lane wave per query edge
// ---------------------------------------------------------------------------
__global__ void edge_score(const float* __restrict__ emb2, const int* __restrict__ eli,
                           const float* __restrict__ ea, const float* __restrict__ pw,
                           const float* __restrict__ pb, float* __restrict__ scores, int Q) {
    int t = blockIdx.x * 256 + threadIdx.x;
    int e = t >> 6, l = t & 63;
    if (e >= Q) return;
    int s = eli[e], d = eli[Q + e];
    float acc = 0.f;
#pragma unroll
    for (int i = 0; i < 2; ++i) {
        int f = l + 64 * i;
        acc += emb2[(long)s * 128 + f] * pw[f] + emb2[(long)d * 128 + f] * pw[128 + f];
    }
    if (l < 16) acc += ea[(long)e * 16 + l] * pw[256 + l];
#pragma unroll
    for (int off = 32; off > 0; off >>= 1) acc += __shfl_down(acc, off);
    if (l == 0) scores[e] = acc + pb[0];
}

// ---------------------------------------------------------------------------

extern "C" void kernel_launch(void* const* d_in, const int* in_sizes, int n_in,
                              void* d_out, int out_size, void* d_ws, size_t ws_size,
                              hipStream_t stream) {
    const float* x       = (const float*)d_in[0];
    const int*   ei      = (const int*)d_in[1];
    const int*   eli     = (const int*)d_in[2];
    const float* eattr   = (const float*)d_in[3];
    const float* prev1   = (const float*)d_in[4];
    const float* prev2   = (const float*)d_in[5];
    const float* pre1_W  = (const float*)d_in[6];
    const float* pre1_b  = (const float*)d_in[7];
    const float* pre2_W  = (const float*)d_in[8];
    const float* pre2_b  = (const float*)d_in[9];
    const float* conv1_W = (const float*)d_in[10];
    const float* conv1_b = (const float*)d_in[11];
    const float* conv2_W = (const float*)d_in[12];
    const float* conv2_b = (const float*)d_in[13];
    const float* g1_Wih  = (const float*)d_in[14];
    const float* g1_Whh  = (const float*)d_in[15];
    const float* g1_bih  = (const float*)d_in[16];
    const float* g1_bhh  = (const float*)d_in[17];
    const float* g2_Wih  = (const float*)d_in[18];
    const float* g2_Whh  = (const float*)d_in[19];
    const float* g2_bih  = (const float*)d_in[20];
    const float* g2_bhh  = (const float*)d_in[21];
    const float* post_W  = (const float*)d_in[22];
    const float* post_b  = (const float*)d_in[23];

    float* out    = (float*)d_out;
    float* scores = out;                      // [NQ]
    float* emb1   = out + NQ;                 // [N,256] (also agg1 scratch)
    float* emb2   = emb1 + (long)NN * 256;    // [N,128] (also agg2 scratch)

    // workspace pools (bytes)
    char* ws = (char*)d_ws;
    const long S256 = MP * 256 * 2;           // 25,624,576
    const long S128 = MP * 128 * 2;
    short* P1 = (short*)ws;                       // hw1b -> hw2b
    short* P2 = (short*)(ws + S256);              // h1b  -> emb1b
    short* P3 = (short*)(ws + 2 * S256);          // h2b  -> agg2b
    short* P4 = (short*)(ws + 2 * S256 + S128);   // p1b  -> p2b
    short* P5 = (short*)(ws + 3 * S256 + S128);   // xb   -> agg1b
    short* WTb   = (short*)(ws + 4 * S256 + S128);
    short* pre1T  = WTb;                    // [256][256]
    short* pre2T  = pre1T + 256 * 256;      // [128][256]
    short* conv1T = pre2T + 128 * 256;      // [256][128]
    short* conv2T = conv1T + 256 * 128;     // [128][256]
    short* g1ihT  = conv2T + 128 * 256;     // [768][256]
    short* g1hhT  = g1ihT + 768 * 256;
    short* g2ihT  = g1hhT + 768 * 256;      // [384][128]
    short* g2hhT  = g2ihT + 384 * 128;
    float* dinv   = (float*)(g2hhT + 384 * 128);

    const int* rows = ei;
    const int* cols = ei + NE;

    dim3 blk(256);

    // --- conversions ---
    f2b_rows<<<(MP * 256 + 255) / 256, blk, 0, stream>>>(x, P5, (long)NN * 256, MP * 256);
    f2b_rows<<<(MP * 256 + 255) / 256, blk, 0, stream>>>(prev1, P4, (long)NN * 256, MP * 256);
    wT_b<<<(256 * 256 + 255) / 256, blk, 0, stream>>>(pre1_W, pre1T, 256, 256);
    wT_b<<<(128 * 256 + 255) / 256, blk, 0, stream>>>(pre2_W, pre2T, 256, 128);
    wT_b<<<(256 * 128 + 255) / 256, blk, 0, stream>>>(conv1_W, conv1T, 128, 256);
    wT_b<<<(128 * 256 + 255) / 256, blk, 0, stream>>>(conv2_W, conv2T, 256, 128);
    wT_b<<<(768 * 256 + 255) / 256, blk, 0, stream>>>(g1_Wih, g1ihT, 256, 768);
    wT_b<<<(768 * 256 + 255) / 256, blk, 0, stream>>>(g1_Whh, g1hhT, 256, 768);
    wT_b<<<(384 * 128 + 255) / 256, blk, 0, stream>>>(g2_Wih, g2ihT, 128, 384);
    wT_b<<<(384 * 128 + 255) / 256, blk, 0, stream>>>(g2_Whh, g2hhT, 128, 384);

    // --- degrees ---
    hipMemsetAsync(dinv, 0, NN * sizeof(float), stream);
    deg_kernel<<<(NE + 255) / 256, blk, 0, stream>>>(cols, dinv, NE);
    dinv_kernel<<<(NN + 255) / 256, blk, 0, stream>>>(dinv, NN);

    // --- dense pre-layers ---
    gemm_mfma<1, false, true><<<dim3(391, 2), blk, 0, stream>>>(P5, pre1T, pre1_b, nullptr, P2, NN, 256, 256);
    gemm_mfma<1, false, true><<<dim3(391, 1), blk, 0, stream>>>(P2, pre2T, pre2_b, nullptr, P3, NN, 128, 256);
    gemm_mfma<0, false, true><<<dim3(391, 2), blk, 0, stream>>>(P3, conv1T, nullptr, nullptr, P1, NN, 256, 128);

    // --- GCN1 aggregate (agg in emb1 region) ---
    hipMemsetAsync(emb1, 0, (size_t)NN * 256 * 4, stream);
    scatter_b<256><<<NE / 4, blk, 0, stream>>>(P1, rows, cols, dinv, emb1, NE);
    finish_agg_b<256><<<((long)NN * 256 + 255) / 256, blk, 0, stream>>>(emb1, P1, dinv, conv1_b, P5, NN);

    // --- GRU1 ---
    gru_mfma<256, true><<<dim3(782, 4), blk, 0, stream>>>(P5, P4, prev1, g1ihT, g1hhT,
                                                          g1_bih, g1_bhh, emb1, P2, NN);

    // --- prev2 conversion (P4 free now) ---
    f2b_rows<<<(MP * 128 + 255) / 256, blk, 0, stream>>>(prev2, P4, (long)NN * 128, MP * 128);

    // --- conv2 ---
    gemm_mfma<0, false, true><<<dim3(391, 1), blk, 0, stream>>>(P2, conv2T, nullptr, nullptr, P1, NN, 128, 256);

    // --- GCN2 aggregate (agg in emb2 region) ---
    hipMemsetAsync(emb2, 0, (size_t)NN * 128 * 4, stream);
    scatter_b<128><<<NE / 4, blk, 0, stream>>>(P1, rows, cols, dinv, emb2, NE);
    finish_agg_b<128><<<((long)NN * 128 + 255) / 256, blk, 0, stream>>>(emb2, P1, dinv, conv2_b, P3, NN);

    // --- GRU2 ---
    gru_mfma<128, false><<<dim3(782, 2), blk, 0, stream>>>(P3, P4, prev2, g2ihT, g2hhT,
                                                           g2_bih, g2_bhh, emb2, nullptr, NN);

    // --- edge scores ---
    edge_score<<<NQ / 4, blk, 0, stream>>>(emb2, eli, eattr, post_W, post_b, scores, NQ);
}

// Round 3
// 585.207 us; speedup vs baseline: 3.6054x; 2.4443x over previous
//
#include <hip/hip_runtime.h>
#include <hip/hip_bf16.h>

#define DEVFN __device__ __forceinline__

constexpr int NN = 50000;
constexpr int NE = 800000;
constexpr int NQ = 200000;
constexpr long MP = 50048;   // NN padded to multiple of 128

typedef __attribute__((ext_vector_type(8))) short bf16x8;
typedef __attribute__((ext_vector_type(4))) short s16x4;
typedef __attribute__((ext_vector_type(2))) short s16x2;
typedef __attribute__((ext_vector_type(4))) float f32x4;
typedef __attribute__((address_space(1))) const void gv_t;
typedef __attribute__((address_space(3))) void lv_t;

DEVFN float lrelu(float x) { return x > 0.f ? x : 0.01f * x; }
DEVFN float sigmoidf(float x) { return 1.f / (1.f + __expf(-x)); }

DEVFN short f2b(float v) {
    __hip_bfloat16 h = __float2bfloat16(v);
    return *reinterpret_cast<short*>(&h);
}
DEVFN float b2f(short s) {
    union { unsigned u; float f; } z;
    z.u = ((unsigned)(unsigned short)s) << 16;
    return z.f;
}
DEVFN void gld16(const void* g, void* l) {
    __builtin_amdgcn_global_load_lds((gv_t*)g, (lv_t*)l, 16, 0, 0);
}

// ---------------------------------------------------------------------------
// fp32 -> bf16 row copy with zero-filled padding rows
// ---------------------------------------------------------------------------
__global__ void f2b_rows(const float* __restrict__ in, short* __restrict__ out,
                         long n, long ntot) {
    long i = (long)blockIdx.x * 256 + threadIdx.x;
    if (i < n) out[i] = f2b(in[i]);
    else if (i < ntot) out[i] = 0;
}

// fp32 [K][N] -> bf16 [N][K] (transposed weights)
__global__ void wT_b(const float* __restrict__ W, short* __restrict__ Wt, int K, int N) {
    int i = blockIdx.x * 256 + threadIdx.x;
    if (i >= N * K) return;
    int n = i / K, k = i % K;
    Wt[i] = f2b(W[(long)k * N + n]);
}

// ---------------------------------------------------------------------------
// bf16 MFMA GEMM: C = epi(A[Mpad][K] @ Bt[Nt][K]^T + bias)
// BM=BN=128, BK=32, 4 waves (2x2), each wave 64x64 (4x4 16x16 frags).
// ---------------------------------------------------------------------------
template <int EPI, bool OUTF, bool OUTB>
__global__ __launch_bounds__(256)
void gemm_mfma(const short* __restrict__ A, const short* __restrict__ Bt,
               const float* __restrict__ bias, float* __restrict__ Cf,
               short* __restrict__ Cb, int M, int Nt, int K) {
    __shared__ alignas(16) short As[128 * 32];
    __shared__ alignas(16) short Bs[128 * 32];
    const int tid = threadIdx.x;
    const int lane = tid & 63, w = tid >> 6;
    const int wr = w >> 1, wc = w & 1;
    const long row0 = (long)blockIdx.x * 128;
    const long col0 = (long)blockIdx.y * 128;

    f32x4 acc[4][4] = {};

    const int ra = tid >> 2;            // 0..63
    const int kc = (tid & 3) * 8;       // element offset in K
    const short* gA = A + (row0 + ra) * (long)K + kc;
    const short* gB = Bt + (col0 + ra) * (long)K + kc;
    short* lA0 = As + tid * 8;
    short* lA1 = As + 2048 + tid * 8;
    short* lB0 = Bs + tid * 8;
    short* lB1 = Bs + 2048 + tid * 8;
    const long half = 64 * (long)K;

    for (int k0 = 0; k0 < K; k0 += 32) {
        gld16(gA + k0, lA0);
        gld16(gA + half + k0, lA1);
        gld16(gB + k0, lB0);
        gld16(gB + half + k0, lB1);
        __syncthreads();
        bf16x8 af[4], bfr[4];
        const int l15 = lane & 15, kq = (lane >> 4) * 8;
#pragma unroll
        for (int i = 0; i < 4; ++i)
            af[i] = *(const bf16x8*)&As[(wr * 64 + i * 16 + l15) * 32 + kq];
#pragma unroll
        for (int j = 0; j < 4; ++j)
            bfr[j] = *(const bf16x8*)&Bs[(wc * 64 + j * 16 + l15) * 32 + kq];
#pragma unroll
        for (int i = 0; i < 4; ++i)
#pragma unroll
            for (int j = 0; j < 4; ++j)
                acc[i][j] = __builtin_amdgcn_mfma_f32_16x16x32_bf16(af[i], bfr[j], acc[i][j], 0, 0, 0);
        __syncthreads();
    }

    const int cr = (lane >> 4) * 4, cc = lane & 15;
#pragma unroll
    for (int i = 0; i < 4; ++i) {
#pragma unroll
        for (int j = 0; j < 4; ++j) {
            const long col = col0 + wc * 64 + j * 16 + cc;
            float bv = (EPI == 1) ? bias[col] : 0.f;
#pragma unroll
            for (int r = 0; r < 4; ++r) {
                const long row = row0 + wr * 64 + i * 16 + cr + r;
                float v = acc[i][j][r];
                if (EPI == 1) v = lrelu(v + bv);
                if (OUTF && row < M) Cf[row * Nt + col] = v;
                if (OUTB) Cb[row * Nt + col] = f2b(v);
            }
        }
    }
}

// ---------------------------------------------------------------------------
// Fused GRU via MFMA: 6 acc tile-sets; tile 64 rows x 64 gate-cols, 4 waves.
// ---------------------------------------------------------------------------
template <int H, bool WRITEB>
__global__ __launch_bounds__(256)
void gru_mfma(const short* __restrict__ Ab, const short* __restrict__ Pb,
              const float* __restrict__ prevf,
              const short* __restrict__ WihT, const short* __restrict__ WhhT,
              const float* __restrict__ bih, const float* __restrict__ bhh,
              float* __restrict__ outF, short* __restrict__ outB, int M) {
    __shared__ alignas(16) short Ah[64 * 32];
    __shared__ alignas(16) short Ap[64 * 32];
    __shared__ alignas(16) short Bs6[6][64 * 32];
    const int tid = threadIdx.x;
    const int lane = tid & 63, w = tid >> 6;
    const int wr = w >> 1, wc = w & 1;
    const long row0 = (long)blockIdx.x * 64;
    const int col0 = blockIdx.y * 64;

    f32x4 acc[6][2][2] = {};

    const int ra = tid >> 2;
    const int kc = (tid & 3) * 8;
    const short* gA = Ab + (row0 + ra) * (long)H + kc;
    const short* gP = Pb + (row0 + ra) * (long)H + kc;
    const short* gW[6];
#pragma unroll
    for (int g = 0; g < 3; ++g) {
        gW[g]     = WihT + (long)(g * H + col0 + ra) * H + kc;
        gW[3 + g] = WhhT + (long)(g * H + col0 + ra) * H + kc;
    }
    short* lA = Ah + tid * 8;
    short* lP = Ap + tid * 8;

    for (int k0 = 0; k0 < H; k0 += 32) {
        gld16(gA + k0, lA);
        gld16(gP + k0, lP);
#pragma unroll
        for (int m = 0; m < 6; ++m)
            gld16(gW[m] + k0, &Bs6[m][tid * 8]);
        __syncthreads();
        const int l15 = lane & 15, kq = (lane >> 4) * 8;
        bf16x8 a2[2], p2[2], bb[6][2];
#pragma unroll
        for (int i = 0; i < 2; ++i) {
            a2[i] = *(const bf16x8*)&Ah[(wr * 32 + i * 16 + l15) * 32 + kq];
            p2[i] = *(const bf16x8*)&Ap[(wr * 32 + i * 16 + l15) * 32 + kq];
        }
#pragma unroll
        for (int m = 0; m < 6; ++m)
#pragma unroll
            for (int j = 0; j < 2; ++j)
                bb[m][j] = *(const bf16x8*)&Bs6[m][(wc * 32 + j * 16 + l15) * 32 + kq];
#pragma unroll
        for (int m = 0; m < 6; ++m)
#pragma unroll
            for (int i = 0; i < 2; ++i)
#pragma unroll
                for (int j = 0; j < 2; ++j)
                    acc[m][i][j] = __builtin_amdgcn_mfma_f32_16x16x32_bf16(
                        (m < 3) ? a2[i] : p2[i], bb[m][j], acc[m][i][j], 0, 0, 0);
        __syncthreads();
    }

    const int cr = (lane >> 4) * 4, cc = lane & 15;
#pragma unroll
    for (int i = 0; i < 2; ++i) {
#pragma unroll
        for (int j = 0; j < 2; ++j) {
            const long col = col0 + wc * 32 + j * 16 + cc;
            const float bi_r = bih[col], bi_z = bih[H + col], bi_n = bih[2 * H + col];
            const float bh_r = bhh[col], bh_z = bhh[H + col], bh_n = bhh[2 * H + col];
#pragma unroll
            for (int r = 0; r < 4; ++r) {
                const long row = row0 + wr * 32 + i * 16 + cr + r;
                if (row >= M) continue;
                float rg = sigmoidf(acc[0][i][j][r] + bi_r + acc[3][i][j][r] + bh_r);
                float zg = sigmoidf(acc[1][i][j][r] + bi_z + acc[4][i][j][r] + bh_z);
                float ng = tanhf(acc[2][i][j][r] + bi_n + rg * (acc[5][i][j][r] + bh_n));
                float o = (1.f - zg) * ng + zg * prevf[row * (long)H + col];
                outF[row * (long)H + col] = o;
                if (WRITEB) outB[row * (long)H + col] = f2b(o);
            }
        }
    }
}

// ---------------------------------------------------------------------------
// CSR build: count -> scan -> fill (edge list sorted by destination col)
// ---------------------------------------------------------------------------
__global__ void cnt_kernel(const int* __restrict__ cols, int* __restrict__ cnt, int E) {
    int e = blockIdx.x * 256 + threadIdx.x;
    if (e < E) atomicAdd(&cnt[cols[e]], 1);
}

__global__ void dinv_kernel(const int* __restrict__ cnt, float* __restrict__ dinv, int n) {
    int i = blockIdx.x * 256 + threadIdx.x;
    if (i < n) dinv[i] = rsqrtf((float)cnt[i] + 1.0f);   // +1 self-loop
}

__global__ void scan1(const int* __restrict__ cnt, int* __restrict__ off,
                      int* __restrict__ bsum, int n) {
    __shared__ int sm[256];
    int i = blockIdx.x * 256 + threadIdx.x;
    int v = (i < n) ? cnt[i] : 0;
    sm[threadIdx.x] = v;
    __syncthreads();
    for (int s = 1; s < 256; s <<= 1) {
        int t = (threadIdx.x >= s) ? sm[threadIdx.x - s] : 0;
        __syncthreads();
        sm[threadIdx.x] += t;
        __syncthreads();
    }
    if (i < n) off[i + 1] = sm[threadIdx.x];
    if (threadIdx.x == 255) bsum[blockIdx.x] = sm[255];
}

__global__ void scan2(int* __restrict__ bsum, int nb) {
    __shared__ int sm[256];
    int v = (threadIdx.x < nb) ? bsum[threadIdx.x] : 0;
    sm[threadIdx.x] = v;
    __syncthreads();
    for (int s = 1; s < 256; s <<= 1) {
        int t = (threadIdx.x >= s) ? sm[threadIdx.x - s] : 0;
        __syncthreads();
        sm[threadIdx.x] += t;
        __syncthreads();
    }
    if (threadIdx.x < nb) bsum[threadIdx.x] = sm[threadIdx.x] - v;  // exclusive
}

__global__ void scan3(int* __restrict__ off, const int* __restrict__ bsum, int n) {
    int i = blockIdx.x * 256 + threadIdx.x;
    if (i < n) off[i + 1] += bsum[blockIdx.x];
    if (i == 0) off[0] = 0;
}

__global__ void fill_csr(const int* __restrict__ rows, const int* __restrict__ cols,
                         const float* __restrict__ dinv, const int* __restrict__ off,
                         int* __restrict__ cursor, int* __restrict__ srow,
                         float* __restrict__ snorm, int E) {
    int e = blockIdx.x * 256 + threadIdx.x;
    if (e >= E) return;
    int r = rows[e], c = cols[e];
    int p = off[c] + atomicAdd(&cursor[c], 1);
    srow[p] = r;
    snorm[p] = dinv[r] * dinv[c];
}

// ---------------------------------------------------------------------------
// Gather-aggregate, fused epilogue: one 64-lane wave per destination node.
// aggb[c] = bf16(lrelu(sum_e hw[srow[e]]*snorm[e] + hw[c]*dinv[c]^2 + bias))
// ---------------------------------------------------------------------------
template <int H>
__global__ __launch_bounds__(256)
void gather_agg(const short* __restrict__ hwb, const int* __restrict__ off,
                const int* __restrict__ srow, const float* __restrict__ snorm,
                const float* __restrict__ dinv, const float* __restrict__ bias,
                short* __restrict__ aggb, int n) {
    constexpr int V = H / 64;           // feats per lane (4 or 2)
    typedef __attribute__((ext_vector_type(V))) short svt;
    int t = blockIdx.x * 256 + threadIdx.x;
    int c = t >> 6, l = t & 63;
    if (c >= n) return;
    const int fo = l * V;
    float acc[V];
    // self loop
    {
        float dd = dinv[c] * dinv[c];
        svt v = *(const svt*)&hwb[(long)c * H + fo];
#pragma unroll
        for (int i = 0; i < V; ++i) acc[i] = b2f(v[i]) * dd;
    }
    int e = off[c];
    const int e1 = off[c + 1];
    for (; e + 1 < e1; e += 2) {
        int r0 = srow[e], r1 = srow[e + 1];
        float n0 = snorm[e], n1 = snorm[e + 1];
        svt v0 = *(const svt*)&hwb[(long)r0 * H + fo];
        svt v1 = *(const svt*)&hwb[(long)r1 * H + fo];
#pragma unroll
        for (int i = 0; i < V; ++i)
            acc[i] += b2f(v0[i]) * n0 + b2f(v1[i]) * n1;
    }
    if (e < e1) {
        int r0 = srow[e];
        float n0 = snorm[e];
        svt v0 = *(const svt*)&hwb[(long)r0 * H + fo];
#pragma unroll
        for (int i = 0; i < V; ++i) acc[i] += b2f(v0[i]) * n0;
    }
    svt o;
#pragma unroll
    for (int i = 0; i < V; ++i) o[i] = f2b(lrelu(acc[i] + bias[fo + i]));
    *(svt*)&aggb[(long)c * H + fo] = o;
}

// ---------------------------------------------------------------------------
// Edge scores: one 64-lane wave per query edge
// ---------------------------------------------------------------------------
__global__ void edge_score(const float* __restrict__ emb2, const int* __restrict__ eli,
                           const float* __restrict__ ea, const float* __restrict__ pw,
                           const float* __restrict__ pb, float* __restrict__ scores, int Q) {
    int t = blockIdx.x * 256 + threadIdx.x;
    int e = t >> 6, l = t & 63;
    if (e >= Q) return;
    int s = eli[e], d = eli[Q + e];
    float acc = 0.f;
#pragma unroll
    for (int i = 0; i < 2; ++i) {
        int f = l + 64 * i;
        acc += emb2[(long)s * 128 + f] * pw[f] + emb2[(long)d * 128 + f] * pw[128 + f];
    }
    if (l < 16) acc += ea[(long)e * 16 + l] * pw[256 + l];
#pragma unroll
    for (int off = 32; off > 0; off >>= 1) acc += __shfl_down(acc, off);
    if (l == 0) scores[e] = acc + pb[0];
}

// ---------------------------------------------------------------------------

extern "C" void kernel_launch(void* const* d_in, const int* in_sizes, int n_in,
                              void* d_out, int out_size, void* d_ws, size_t ws_size,
                              hipStream_t stream) {
    const float* x       = (const float*)d_in[0];
    const int*   ei      = (const int*)d_in[1];
    const int*   eli     = (const int*)d_in[2];
    const float* eattr   = (const float*)d_in[3];
    const float* prev1   = (const float*)d_in[4];
    const float* prev2   = (const float*)d_in[5];
    const float* pre1_W  = (const float*)d_in[6];
    const float* pre1_b  = (const float*)d_in[7];
    const float* pre2_W  = (const float*)d_in[8];
    const float* pre2_b  = (const float*)d_in[9];
    const float* conv1_W = (const float*)d_in[10];
    const float* conv1_b = (const float*)d_in[11];
    const float* conv2_W = (const float*)d_in[12];
    const float* conv2_b = (const float*)d_in[13];
    const float* g1_Wih  = (const float*)d_in[14];
    const float* g1_Whh  = (const float*)d_in[15];
    const float* g1_bih  = (const float*)d_in[16];
    const float* g1_bhh  = (const float*)d_in[17];
    const float* g2_Wih  = (const float*)d_in[18];
    const float* g2_Whh  = (const float*)d_in[19];
    const float* g2_bih  = (const float*)d_in[20];
    const float* g2_bhh  = (const float*)d_in[21];
    const float* post_W  = (const float*)d_in[22];
    const float* post_b  = (const float*)d_in[23];

    float* out    = (float*)d_out;
    float* scores = out;                      // [NQ]
    float* emb1   = out + NQ;                 // [N,256]
    float* emb2   = emb1 + (long)NN * 256;    // [N,128]

    // workspace layout (bytes)
    char* ws = (char*)d_ws;
    const long S256 = MP * 256 * 2;           // 25,624,576
    const long S128 = MP * 128 * 2;
    short* R1 = (short*)ws;                       // xb   -> hw1b
    short* R2 = (short*)(ws + S256);              // h1b  -> agg1b
    short* R3 = (short*)(ws + 2 * S256);          // h2b  -> hw2b   (S128)
    short* R4 = (short*)(ws + 2 * S256 + S128);   // p1b  -> p2b    (S256)
    short* R4b = (short*)(ws + 2 * S256 + 2 * S128);  // agg2b (2nd half of R4)
    short* R5 = (short*)(ws + 3 * S256 + S128);   // emb1b
    short* WTb   = (short*)(ws + 4 * S256 + S128);
    short* pre1T  = WTb;                    // [256][256]
    short* pre2T  = pre1T + 256 * 256;      // [128][256]
    short* conv1T = pre2T + 128 * 256;      // [256][128]
    short* conv2T = conv1T + 256 * 128;     // [128][256]
    short* g1ihT  = conv2T + 128 * 256;     // [768][256]
    short* g1hhT  = g1ihT + 768 * 256;
    short* g2ihT  = g1hhT + 768 * 256;      // [384][128]
    short* g2hhT  = g2ihT + 384 * 128;
    float* dinv   = (float*)(g2hhT + 384 * 128);  // [NN]
    int*   cnt    = (int*)(dinv + NN);            // [NN]
    int*   off    = cnt + NN;                     // [NN+1]
    int*   cursor = off + NN + 1;                 // [NN]
    int*   bsum   = cursor + NN;                  // [256]
    int*   srow   = bsum + 256;                   // [NE]
    float* snorm  = (float*)(srow + NE);          // [NE]

    const int* rows = ei;
    const int* cols = ei + NE;

    dim3 blk(256);
    const int NB = (NN + 255) / 256;   // 196

    // --- conversions ---
    f2b_rows<<<(MP * 256 + 255) / 256, blk, 0, stream>>>(x, R1, (long)NN * 256, MP * 256);
    f2b_rows<<<(MP * 256 + 255) / 256, blk, 0, stream>>>(prev1, R4, (long)NN * 256, MP * 256);
    wT_b<<<(256 * 256 + 255) / 256, blk, 0, stream>>>(pre1_W, pre1T, 256, 256);
    wT_b<<<(128 * 256 + 255) / 256, blk, 0, stream>>>(pre2_W, pre2T, 256, 128);
    wT_b<<<(256 * 128 + 255) / 256, blk, 0, stream>>>(conv1_W, conv1T, 128, 256);
    wT_b<<<(128 * 256 + 255) / 256, blk, 0, stream>>>(conv2_W, conv2T, 256, 128);
    wT_b<<<(768 * 256 + 255) / 256, blk, 0, stream>>>(g1_Wih, g1ihT, 256, 768);
    wT_b<<<(768 * 256 + 255) / 256, blk, 0, stream>>>(g1_Whh, g1hhT, 256, 768);
    wT_b<<<(384 * 128 + 255) / 256, blk, 0, stream>>>(g2_Wih, g2ihT, 128, 384);
    wT_b<<<(384 * 128 + 255) / 256, blk, 0, stream>>>(g2_Whh, g2hhT, 128, 384);

    // --- CSR build (once, reused by both layers) ---
    hipMemsetAsync(cnt, 0, NN * sizeof(int), stream);
    cnt_kernel<<<(NE + 255) / 256, blk, 0, stream>>>(cols, cnt, NE);
    dinv_kernel<<<NB, blk, 0, stream>>>(cnt, dinv, NN);
    scan1<<<NB, blk, 0, stream>>>(cnt, off, bsum, NN);
    scan2<<<1, blk, 0, stream>>>(bsum, NB);
    scan3<<<NB, blk, 0, stream>>>(off, bsum, NN);
    hipMemsetAsync(cursor, 0, NN * sizeof(int), stream);
    fill_csr<<<(NE + 255) / 256, blk, 0, stream>>>(rows, cols, dinv, off, cursor, srow, snorm, NE);

    // --- dense pre-layers ---
    gemm_mfma<1, false, true><<<dim3(391, 2), blk, 0, stream>>>(R1, pre1T, pre1_b, nullptr, R2, NN, 256, 256);
    gemm_mfma<1, false, true><<<dim3(391, 1), blk, 0, stream>>>(R2, pre2T, pre2_b, nullptr, R3, NN, 128, 256);
    gemm_mfma<0, false, true><<<dim3(391, 2), blk, 0, stream>>>(R3, conv1T, nullptr, nullptr, R1, NN, 256, 128);

    // --- GCN1 aggregate (fused self-loop+bias+lrelu) ---
    gather_agg<256><<<(NN + 3) / 4, blk, 0, stream>>>(R1, off, srow, snorm, dinv, conv1_b, R2, NN);

    // --- GRU1 ---
    gru_mfma<256, true><<<dim3(782, 4), blk, 0, stream>>>(R2, R4, prev1, g1ihT, g1hhT,
                                                          g1_bih, g1_bhh, emb1, R5, NN);

    // --- prev2 conversion (R4 free now) ---
    f2b_rows<<<(MP * 128 + 255) / 256, blk, 0, stream>>>(prev2, R4, (long)NN * 128, MP * 128);

    // --- conv2 ---
    gemm_mfma<0, false, true><<<dim3(391, 1), blk, 0, stream>>>(R5, conv2T, nullptr, nullptr, R3, NN, 128, 256);

    // --- GCN2 aggregate ---
    gather_agg<128><<<(NN + 3) / 4, blk, 0, stream>>>(R3, off, srow, snorm, dinv, conv2_b, R4b, NN);

    // --- GRU2 ---
    gru_mfma<128, false><<<dim3(782, 2), blk, 0, stream>>>(R4b, R4, prev2, g2ihT, g2hhT,
                                                           g2_bih, g2_bhh, emb2, nullptr, NN);

    // --- edge scores ---
    edge_score<<<NQ / 4, blk, 0, stream>>>(emb2, eli, eattr, post_W, post_b, scores, NQ);
}